// Round 13
// baseline (557.285 us; speedup 1.0000x reference)
//
#include <hip/hip_runtime.h>

#define NN 50000
#define NE 800000
#define NT 850000   // NE + NN self loops
#define NG 512
#define NSB 49      // scan blocks: ceil(NN/1024)
#define HB 3321     // hist blocks (NT/256)
#define CB 606      // cvtW blocks (155136/256)
#define GB 196      // goffs blocks (NN/256)

typedef __attribute__((ext_vector_type(8))) short bf16x8;
typedef __attribute__((ext_vector_type(4))) float f32x4;

// ==================== reduction / math helpers ====================

template <int CTRL>
__device__ __forceinline__ float dpp_add(float x) {
  int y = __builtin_amdgcn_update_dpp(0, __float_as_int(x), CTRL, 0xF, 0xF, true);
  return x + __int_as_float(y);
}
template <int CTRL>
__device__ __forceinline__ float dpp_max(float x) {
  int y = __builtin_amdgcn_update_dpp(0, __float_as_int(x), CTRL, 0xF, 0xF, true);
  return fmaxf(x, __int_as_float(y));
}

__device__ __forceinline__ float swz16(float x) {
  return __int_as_float(__builtin_amdgcn_ds_swizzle(__float_as_int(x), 0x401F)); // xor16
}

__device__ __forceinline__ float rowsum16(float x) {
  x = dpp_add<0xB1>(x);
  x = dpp_add<0x4E>(x);
  x = dpp_add<0x124>(x);
  x = dpp_add<0x128>(x);
  return x;
}
__device__ __forceinline__ float quadsum4(float x) {
  x = dpp_add<0xB1>(x);
  x = dpp_add<0x4E>(x);
  return x;
}
__device__ __forceinline__ float xg_sum(float x) {
  x += swz16(x);
  auto p = __builtin_amdgcn_permlane32_swap(__float_as_uint(x), __float_as_uint(x), false, false);
  return __uint_as_float(p[0]) + __uint_as_float(p[1]);
}
__device__ __forceinline__ float xg_max(float x) {
  x = fmaxf(x, swz16(x));
  auto p = __builtin_amdgcn_permlane32_swap(__float_as_uint(x), __float_as_uint(x), false, false);
  return fmaxf(__uint_as_float(p[0]), __uint_as_float(p[1]));
}
__device__ __forceinline__ float xq_sum(float x) {
  x = dpp_add<0x124>(x);
  x = dpp_add<0x128>(x);
  return xg_sum(x);
}
__device__ __forceinline__ float xq_max(float x) {
  x = dpp_max<0x124>(x);
  x = dpp_max<0x128>(x);
  return xg_max(x);
}

__device__ __forceinline__ float exp2_fast(float x) {
#if __has_builtin(__builtin_amdgcn_exp2f)
  return __builtin_amdgcn_exp2f(x);
#else
  return exp2f(x);
#endif
}

__device__ __forceinline__ float lrelu(float t) { return fmaxf(t, 0.2f * t); }

// f32 -> bf16 (RNE)
__device__ __forceinline__ unsigned int f2bf(float f) {
  unsigned int u = __float_as_uint(f);
  u = (u + 0x7FFFu + ((u >> 16) & 1u)) >> 16;
  return u;
}
__device__ __forceinline__ float bf_lo(unsigned int u) { return __uint_as_float(u << 16); }
__device__ __forceinline__ float bf_hi(unsigned int u) { return __uint_as_float(u & 0xFFFF0000u); }
__device__ __forceinline__ float4 bf2f4(uint2 u) {
  return make_float4(bf_lo(u.x), bf_hi(u.x), bf_lo(u.y), bf_hi(u.y));
}

// packed f32 ops (VOP3P; proven on gfx950 via gemm pk_l/pk_h usage)
__device__ __forceinline__ float2 pk_add2(float2 a, float2 b) {
  float2 d;
  asm("v_pk_add_f32 %0, %1, %2" : "=v"(d) : "v"(a), "v"(b));
  return d;
}
__device__ __forceinline__ float2 pk_mul2(float2 a, float2 b) {
  float2 d;
  asm("v_pk_mul_f32 %0, %1, %2" : "=v"(d) : "v"(a), "v"(b));
  return d;
}
__device__ __forceinline__ float2 pk_fma2(float2 a, float2 b, float2 c) {
  float2 d = c;
  asm("v_pk_fma_f32 %0, %1, %2, %0" : "+v"(d) : "v"(a), "v"(b));
  return d;
}
// d += a.lo (broadcast) * b
__device__ __forceinline__ void pk_l(float2& d, float2 a, float2 b) {
  asm("v_pk_fma_f32 %0, %1, %2, %0 op_sel_hi:[0,1,1]" : "+v"(d) : "v"(a), "v"(b));
}
__device__ __forceinline__ void pk_h(float2& d, float2 a, float2 b) {
  asm("v_pk_fma_f32 %0, %1, %2, %0 op_sel:[1,0,0]" : "+v"(d) : "v"(a), "v"(b));
}

// ==================== fused preprocess: hist | cvtW | goffs ====================

__global__ void k_pre(const int* __restrict__ dst, int* __restrict__ cnt,
                      const float* __restrict__ wa, const float* __restrict__ wbp,
                      const float* __restrict__ wc, const float* __restrict__ wd,
                      const float* __restrict__ we, const float* __restrict__ wf,
                      unsigned short* __restrict__ wout,
                      const int* __restrict__ batch, int* __restrict__ goffs) {
  int b = blockIdx.x;
  int tid = threadIdx.x;
  if (b < HB) {
    int i = b * 256 + tid;
    if (i < NT) {
      int d = (i < NE) ? dst[i] : (i - NE);
      atomicAdd(&cnt[d], 1);
    }
  } else if (b < HB + CB) {
    int i = (b - HB) * 256 + tid;
    if (i < 155136) {
      float v;
      if      (i < 36864)  v = wa[i];
      else if (i < 73728)  v = wbp[i - 36864];
      else if (i < 110592) v = wc[i - 73728];
      else if (i < 147456) v = wd[i - 110592];
      else if (i < 151296) v = we[i - 147456];
      else                 v = wf[i - 151296];
      wout[i] = (unsigned short)f2bf(v);
    }
  } else {
    int i = (b - HB - CB) * 256 + tid;
    if (i < NN) {
      int bb = batch[i];
      if (i == 0) {
        for (int g = 0; g <= bb; ++g) goffs[g] = 0;
      } else {
        int pb = batch[i - 1];
        for (int g = pb + 1; g <= bb; ++g) goffs[g] = i;
      }
      if (i == NN - 1) {
        for (int g = bb + 1; g <= NG; ++g) goffs[g] = NN;
      }
    }
  }
}

// ==================== scan (3-phase) + scatter ====================

__global__ __launch_bounds__(1024)
void k_scanA(const int* __restrict__ cnt, int* __restrict__ offs, int* __restrict__ bsum) {
  __shared__ int sh[1024];
  int tid = threadIdx.x;
  int idx = blockIdx.x * 1024 + tid;
  int v = (idx < NN) ? cnt[idx] : 0;
  sh[tid] = v;
  __syncthreads();
  for (int off = 1; off < 1024; off <<= 1) {
    int t = (tid >= off) ? sh[tid - off] : 0;
    __syncthreads();
    sh[tid] += t;
    __syncthreads();
  }
  if (idx < NN) offs[idx] = sh[tid] - v;
  if (tid == 1023) bsum[blockIdx.x] = sh[1023];
}

__global__ void k_scanB(int* __restrict__ bsum, int* __restrict__ offs) {
  int tot = 0;
#pragma unroll 7
  for (int i = 0; i < NSB; ++i) {
    int v = bsum[i];
    bsum[i] = tot;
    tot += v;
  }
  offs[NN] = tot;
}

__global__ __launch_bounds__(1024)
void k_scanC(int* __restrict__ offs, const int* __restrict__ bsum) {
  int idx = blockIdx.x * 1024 + threadIdx.x;
  if (idx < NN) offs[idx] += bsum[blockIdx.x];
}

__global__ void k_scatter(const int* __restrict__ src, const int* __restrict__ dst,
                          const int* __restrict__ offs, int* __restrict__ cur,
                          int* __restrict__ srt) {
  int i = blockIdx.x * blockDim.x + threadIdx.x;
  if (i < NT) {
    int s, d;
    if (i < NE) { s = src[i]; d = dst[i]; }
    else        { s = d = i - NE; }
    int pos = offs[d] + atomicAdd(&cur[d], 1);
    srt[pos] = s;
  }
}

// ==================== dual MFMA GEMM, no-LDS direct-global fragments (K=192) ====================
// grid (FO/64, M/64): consecutive blocks share the A-tile (mb from blockIdx.y).

__global__ __launch_bounds__(256)
void k_gemm_mfma2(const unsigned short* __restrict__ Abf,
                  const unsigned short* __restrict__ W1bf,
                  const unsigned short* __restrict__ W2bf,
                  const float* __restrict__ bias1, const float* __restrict__ bias2,
                  unsigned short* __restrict__ C1, unsigned short* __restrict__ C2,
                  int M, int FO) {
  int tid = threadIdx.x;
  int l = tid & 63, wid = tid >> 6;
  int mb = blockIdx.y * 64, nb = blockIdx.x * 64;
  int wr = (wid >> 1) * 32, wc = (wid & 1) * 32;
  int lr = l & 15, lk = (l >> 4) * 8;

  int ar0 = min(mb + wr +  0 + lr, M - 1);
  int ar1 = min(mb + wr + 16 + lr, M - 1);
  int bc0 = min(nb + wc +  0 + lr, FO - 1);
  int bc1 = min(nb + wc + 16 + lr, FO - 1);
  const unsigned short* pa0 = Abf  + (size_t)ar0 * 192 + lk;
  const unsigned short* pa1 = Abf  + (size_t)ar1 * 192 + lk;
  const unsigned short* q10 = W1bf + (size_t)bc0 * 192 + lk;
  const unsigned short* q11 = W1bf + (size_t)bc1 * 192 + lk;
  const unsigned short* q20 = W2bf + (size_t)bc0 * 192 + lk;
  const unsigned short* q21 = W2bf + (size_t)bc1 * 192 + lk;

  f32x4 acc[2][2][2];
#pragma unroll
  for (int a = 0; a < 2; ++a)
#pragma unroll
    for (int b = 0; b < 2; ++b)
#pragma unroll
      for (int c = 0; c < 2; ++c) acc[a][b][c] = (f32x4){0.f, 0.f, 0.f, 0.f};

#pragma unroll
  for (int kt = 0; kt < 6; ++kt) {
    bf16x8 a0  = *(const bf16x8*)(pa0 + kt * 32);
    bf16x8 a1  = *(const bf16x8*)(pa1 + kt * 32);
    bf16x8 b10 = *(const bf16x8*)(q10 + kt * 32);
    bf16x8 b11 = *(const bf16x8*)(q11 + kt * 32);
    bf16x8 b20 = *(const bf16x8*)(q20 + kt * 32);
    bf16x8 b21 = *(const bf16x8*)(q21 + kt * 32);
    acc[0][0][0] = __builtin_amdgcn_mfma_f32_16x16x32_bf16(a0, b10, acc[0][0][0], 0, 0, 0);
    acc[0][0][1] = __builtin_amdgcn_mfma_f32_16x16x32_bf16(a0, b11, acc[0][0][1], 0, 0, 0);
    acc[0][1][0] = __builtin_amdgcn_mfma_f32_16x16x32_bf16(a1, b10, acc[0][1][0], 0, 0, 0);
    acc[0][1][1] = __builtin_amdgcn_mfma_f32_16x16x32_bf16(a1, b11, acc[0][1][1], 0, 0, 0);
    acc[1][0][0] = __builtin_amdgcn_mfma_f32_16x16x32_bf16(a0, b20, acc[1][0][0], 0, 0, 0);
    acc[1][0][1] = __builtin_amdgcn_mfma_f32_16x16x32_bf16(a0, b21, acc[1][0][1], 0, 0, 0);
    acc[1][1][0] = __builtin_amdgcn_mfma_f32_16x16x32_bf16(a1, b20, acc[1][1][0], 0, 0, 0);
    acc[1][1][1] = __builtin_amdgcn_mfma_f32_16x16x32_bf16(a1, b21, acc[1][1][1], 0, 0, 0);
  }

  int rb = (l >> 4) * 4;
#pragma unroll
  for (int mt = 0; mt < 2; ++mt) {
    unsigned short* C = mt == 0 ? C1 : C2;
    const float* bias = mt == 0 ? bias1 : bias2;
#pragma unroll
    for (int fn = 0; fn < 2; ++fn) {
      int col = nb + wc + fn * 16 + lr;
      if (col >= FO) continue;
      float bv = bias[col];
#pragma unroll
      for (int fm = 0; fm < 2; ++fm) {
        const f32x4& av = acc[mt][fm][fn];
#pragma unroll
        for (int i = 0; i < 4; ++i) {
          int row = mb + wr + fm * 16 + rb + i;
          if (row < M) C[(size_t)row * FO + col] = (unsigned short)f2bf(av[i] + bv);
        }
      }
    }
  }
}

// ==================== f32 dual GEMM (layer 0, K=11) -> bf16 outputs ====================

__global__ __launch_bounds__(256)
void k_gemm_dual(const float* __restrict__ A, int M, int K, int FO,
                 const float* __restrict__ W1, const float* __restrict__ bias1,
                 const float* __restrict__ W2, const float* __restrict__ bias2,
                 unsigned short* __restrict__ C1, unsigned short* __restrict__ C2) {
  constexpr int CT = 16;
  constexpr int BN = CT * 4;
  constexpr int BR = (256 / CT) * 8;
  constexpr int AF4 = BR / 64;
  __shared__ float As[16][BR + 4];
  __shared__ float Bs[2][16][BN + 4];

  int tid = threadIdx.x;
  int tx = tid % CT, ty = tid / CT;
  int mb = blockIdx.x * BR, nb = blockIdx.y * BN;
  int nkt = (K + 15) >> 4;

  float4 sa[AF4], sb1, sb2;

  auto ldrow = [&](const float* P, int row, int lim, int k0, int kq) -> float4 {
    float4 v = make_float4(0.f, 0.f, 0.f, 0.f);
    if (row < lim) {
      float t[4];
#pragma unroll
      for (int i = 0; i < 4; ++i)
        t[i] = (k0 + kq + i < K) ? P[(size_t)row * K + k0 + kq + i] : 0.f;
      v = make_float4(t[0], t[1], t[2], t[3]);
    }
    return v;
  };

  auto loadg = [&](int kt) {
    int k0 = kt * 16;
#pragma unroll
    for (int q = 0; q < AF4; ++q) {
      int f4 = q * 256 + tid;
      sa[q] = ldrow(A, mb + (f4 >> 2), M, k0, (f4 & 3) * 4);
    }
    int row = tid >> 2, kq = (tid & 3) * 4;
    sb1 = ldrow(W1, nb + row, FO, k0, kq);
    sb2 = ldrow(W2, nb + row, FO, k0, kq);
  };

  auto stlds = [&]() {
#pragma unroll
    for (int q = 0; q < AF4; ++q) {
      int f4 = q * 256 + tid;
      int row = f4 >> 2, kq = (f4 & 3) * 4;
      As[kq + 0][row] = sa[q].x; As[kq + 1][row] = sa[q].y;
      As[kq + 2][row] = sa[q].z; As[kq + 3][row] = sa[q].w;
    }
    int row = tid >> 2, kq = (tid & 3) * 4;
    Bs[0][kq + 0][row] = sb1.x; Bs[0][kq + 1][row] = sb1.y;
    Bs[0][kq + 2][row] = sb1.z; Bs[0][kq + 3][row] = sb1.w;
    Bs[1][kq + 0][row] = sb2.x; Bs[1][kq + 1][row] = sb2.y;
    Bs[1][kq + 2][row] = sb2.z; Bs[1][kq + 3][row] = sb2.w;
  };

  float2 c1[8][2], c2[8][2];
#pragma unroll
  for (int r = 0; r < 8; ++r)
#pragma unroll
    for (int j = 0; j < 2; ++j) {
      c1[r][j] = make_float2(0.f, 0.f);
      c2[r][j] = make_float2(0.f, 0.f);
    }

  loadg(0);
  stlds();
  __syncthreads();

  for (int t = 0;;) {
#pragma unroll
    for (int k = 0; k < 16; ++k) {
      float4 av0 = *(const float4*)&As[k][ty * 8 + 0];
      float4 av1 = *(const float4*)&As[k][ty * 8 + 4];
      float4 bv1 = *(const float4*)&Bs[0][k][tx * 4];
      float4 bv2 = *(const float4*)&Bs[1][k][tx * 4];
      float2 f1a = make_float2(bv1.x, bv1.y), f1b = make_float2(bv1.z, bv1.w);
      float2 f2a = make_float2(bv2.x, bv2.y), f2b = make_float2(bv2.z, bv2.w);
      float2 a01 = make_float2(av0.x, av0.y), a23 = make_float2(av0.z, av0.w);
      float2 a45 = make_float2(av1.x, av1.y), a67 = make_float2(av1.z, av1.w);
#define PKROW(rp, a)                                                       \
      pk_l(c1[2 * rp + 0][0], a, f1a); pk_l(c1[2 * rp + 0][1], a, f1b);    \
      pk_h(c1[2 * rp + 1][0], a, f1a); pk_h(c1[2 * rp + 1][1], a, f1b);    \
      pk_l(c2[2 * rp + 0][0], a, f2a); pk_l(c2[2 * rp + 0][1], a, f2b);    \
      pk_h(c2[2 * rp + 1][0], a, f2a); pk_h(c2[2 * rp + 1][1], a, f2b);
      PKROW(0, a01) PKROW(1, a23) PKROW(2, a45) PKROW(3, a67)
#undef PKROW
    }
    if (++t == nkt) break;
    loadg(t);
    __syncthreads();
    stlds();
    __syncthreads();
  }

  int col = nb + tx * 4;
  if (col < FO) {
    float4 bb1 = *(const float4*)&bias1[col];
    float4 bb2 = *(const float4*)&bias2[col];
#pragma unroll
    for (int r = 0; r < 8; ++r) {
      int m = mb + ty * 8 + r;
      if (m >= M) continue;
      uint2 o1, o2;
      o1.x = f2bf(c1[r][0].x + bb1.x) | (f2bf(c1[r][0].y + bb1.y) << 16);
      o1.y = f2bf(c1[r][1].x + bb1.z) | (f2bf(c1[r][1].y + bb1.w) << 16);
      o2.x = f2bf(c2[r][0].x + bb2.x) | (f2bf(c2[r][0].y + bb2.y) << 16);
      o2.y = f2bf(c2[r][1].x + bb2.z) | (f2bf(c2[r][1].y + bb2.w) << 16);
      *(uint2*)&C1[(size_t)m * FO + col] = o1;
      *(uint2*)&C2[(size_t)m * FO + col] = o2;
    }
  }
}

// ==================== GAT H=3 C=64: 4 edges/wave, packed-f32 score/acc ====================
// Structure identical to R10 (depth-1 prefetch); only the per-channel math is packed.

__global__ __launch_bounds__(256)
void k_gat3(const unsigned short* __restrict__ xl, const unsigned short* __restrict__ xr,
            const float* __restrict__ att, const float* __restrict__ bias,
            const int* __restrict__ offs, const int* __restrict__ srt,
            unsigned short* __restrict__ obf, int relu) {
  const float L2E = 1.4426950408889634f;
  int lane = threadIdx.x & 63;
  int grp = lane >> 4, lg = lane & 15;
  int n = blockIdx.x * 4 + (threadIdx.x >> 6);
  if (n >= NN) return;
  const float2 C06 = make_float2(0.6f, 0.6f);
  const float2 C04 = make_float2(0.4f, 0.4f);

  float2 xrp[6], atp[6];
#pragma unroll
  for (int h = 0; h < 3; ++h) {
    uint2 u = *(const uint2*)(xr + (size_t)n * 192 + h * 64 + lg * 4);
    xrp[h * 2 + 0] = make_float2(bf_lo(u.x), bf_hi(u.x));
    xrp[h * 2 + 1] = make_float2(bf_lo(u.y), bf_hi(u.y));
    float4 a = *(const float4*)&att[h * 64 + lg * 4];
    atp[h * 2 + 0] = make_float2(a.x * L2E, a.y * L2E);
    atp[h * 2 + 1] = make_float2(a.z * L2E, a.w * L2E);
  }
  float m[3] = {-1e30f, -1e30f, -1e30f}, dd[3] = {0.f, 0.f, 0.f};
  float2 ac[6];
#pragma unroll
  for (int i = 0; i < 6; ++i) ac[i] = make_float2(0.f, 0.f);

  int e0 = offs[n], e1 = offs[n + 1];
  int nch = (e1 - e0 + 3) >> 2;

  uint2 Rc[3];
  bool vc;
  int j = e0 + grp;
  {
    int jj = min(j, e1 - 1);
    int s = srt[jj];
    const unsigned short* b = xl + (size_t)s * 192 + lg * 4;
    Rc[0] = *(const uint2*)(b);
    Rc[1] = *(const uint2*)(b + 64);
    Rc[2] = *(const uint2*)(b + 128);
    vc = j < e1;
  }
  for (int it = 0; it < nch; ++it) {
    uint2 Rn[3];
    bool vn = false;
    int jn = j + 4;
    if (it + 1 < nch) {
      int jj = min(jn, e1 - 1);
      int s = srt[jj];
      const unsigned short* b = xl + (size_t)s * 192 + lg * 4;
      Rn[0] = *(const uint2*)(b);
      Rn[1] = *(const uint2*)(b + 64);
      Rn[2] = *(const uint2*)(b + 128);
      vn = jn < e1;
    }
    float2 X[6];
    float part[3];
#pragma unroll
    for (int h = 0; h < 3; ++h) {
      X[h * 2 + 0] = make_float2(bf_lo(Rc[h].x), bf_hi(Rc[h].x));
      X[h * 2 + 1] = make_float2(bf_lo(Rc[h].y), bf_hi(Rc[h].y));
      float2 t0 = pk_add2(X[h * 2 + 0], xrp[h * 2 + 0]);
      float2 t1 = pk_add2(X[h * 2 + 1], xrp[h * 2 + 1]);
      float2 b0 = make_float2(fabsf(t0.x), fabsf(t0.y));
      float2 b1 = make_float2(fabsf(t1.x), fabsf(t1.y));
      float2 l0 = pk_fma2(t0, C06, pk_mul2(b0, C04));   // lrelu = 0.6t + 0.4|t|
      float2 l1 = pk_fma2(t1, C06, pk_mul2(b1, C04));
      float2 ps = pk_mul2(l0, atp[h * 2 + 0]);
      ps = pk_fma2(l1, atp[h * 2 + 1], ps);
      part[h] = ps.x + ps.y;
    }
#pragma unroll
    for (int h = 0; h < 3; ++h) {
      part[h] = rowsum16(part[h]);
      part[h] = vc ? part[h] : -1e30f;
    }
    float g = fmaxf(fmaxf(part[0] - m[0], part[1] - m[1]), part[2] - m[2]);
    if (__any(g > 11.0f)) {   // rare rescale (defer-max), log2 domain
#pragma unroll
      for (int h = 0; h < 3; ++h) {
        float nm = fmaxf(m[h], part[h]);
        float sc = exp2_fast(m[h] - nm);
        dd[h] *= sc;
        ac[h * 2 + 0].x *= sc; ac[h * 2 + 0].y *= sc;
        ac[h * 2 + 1].x *= sc; ac[h * 2 + 1].y *= sc;
        m[h] = nm;
      }
    }
#pragma unroll
    for (int h = 0; h < 3; ++h) {
      float p = vc ? exp2_fast(part[h] - m[h]) : 0.f;
      dd[h] += p;
      float2 P = make_float2(p, p);
      pk_l(ac[h * 2 + 0], P, X[h * 2 + 0]);
      pk_l(ac[h * 2 + 1], P, X[h * 2 + 1]);
    }
    Rc[0] = Rn[0]; Rc[1] = Rn[1]; Rc[2] = Rn[2];
    vc = vn; j = jn;
  }

  // combine the 4 group-partials (once per node)
#pragma unroll
  for (int h = 0; h < 3; ++h) {
    float nm = xg_max(m[h]);
    float sc = exp2_fast(m[h] - nm);
    float D  = xg_sum(dd[h] * sc);
    float A0 = xg_sum(ac[h * 2 + 0].x * sc);
    float A1 = xg_sum(ac[h * 2 + 0].y * sc);
    float A2 = xg_sum(ac[h * 2 + 1].x * sc);
    float A3 = xg_sum(ac[h * 2 + 1].y * sc);
    if (grp == 0) {
      float4 bb = *(const float4*)&bias[h * 64 + lg * 4];
      float inv = 1.0f / D;
      float v0 = fmaf(A0, inv, bb.x);
      float v1 = fmaf(A1, inv, bb.y);
      float v2 = fmaf(A2, inv, bb.z);
      float v3 = fmaf(A3, inv, bb.w);
      if (relu) {
        v0 = fmaxf(v0, 0.f); v1 = fmaxf(v1, 0.f);
        v2 = fmaxf(v2, 0.f); v3 = fmaxf(v3, 0.f);
      }
      unsigned int lo = f2bf(v0) | (f2bf(v1) << 16);
      unsigned int hi = f2bf(v2) | (f2bf(v3) << 16);
      *(uint2*)(obf + (size_t)n * 192 + h * 64 + lg * 4) = make_uint2(lo, hi);
    }
  }
}

// ==================== GAT layer 3 (H=1, C=20): dense per-node output ====================

__global__ __launch_bounds__(256)
void k_gat1(const unsigned short* __restrict__ xl, const unsigned short* __restrict__ xr,
            const float* __restrict__ att, const float* __restrict__ bias,
            const int* __restrict__ offs, const int* __restrict__ srt,
            float* __restrict__ hout) {
  const float L2E = 1.4426950408889634f;
  int lane = threadIdx.x & 63;
  int grp = lane >> 2, lg = lane & 3;
  int n = blockIdx.x * 4 + (threadIdx.x >> 6);
  if (n >= NN) return;

  float xrv[5], atv[5];
#pragma unroll
  for (int i = 0; i < 5; ++i) {
    xrv[i] = bf_lo(xr[(size_t)n * 20 + lg * 5 + i]);
    atv[i] = att[lg * 5 + i] * L2E;
  }
  float m = -1e30f, d = 0.f, a[5] = {0.f, 0.f, 0.f, 0.f, 0.f};

  int e0 = offs[n], e1 = offs[n + 1];
  int nch = (e1 - e0 + 15) >> 4;

  float Xc[5];
  bool vc;
  int j = e0 + grp;
  {
    int jj = min(j, e1 - 1);
    int s = srt[jj];
    const unsigned short* b = xl + (size_t)s * 20 + lg * 5;
#pragma unroll
    for (int i = 0; i < 5; ++i) Xc[i] = bf_lo(b[i]);
    vc = j < e1;
  }
  for (int it = 0; it < nch; ++it) {
    float Xn[5] = {0.f, 0.f, 0.f, 0.f, 0.f};
    bool vn = false;
    int jn = j + 16;
    if (it + 1 < nch) {
      int jj = min(jn, e1 - 1);
      int s = srt[jj];
      const unsigned short* b = xl + (size_t)s * 20 + lg * 5;
#pragma unroll
      for (int i = 0; i < 5; ++i) Xn[i] = bf_lo(b[i]);
      vn = jn < e1;
    }
    float pa = lrelu(Xc[0] + xrv[0]) * atv[0];
#pragma unroll
    for (int i = 1; i < 5; ++i) pa = fmaf(lrelu(Xc[i] + xrv[i]), atv[i], pa);
    pa = quadsum4(pa);
    pa = vc ? pa : -1e30f;
    if (__any(pa - m > 11.0f)) {
      float nm = fmaxf(m, pa);
      float sc = exp2_fast(m - nm);
      d *= sc;
#pragma unroll
      for (int i = 0; i < 5; ++i) a[i] *= sc;
      m = nm;
    }
    float p = vc ? exp2_fast(pa - m) : 0.f;
    d += p;
#pragma unroll
    for (int i = 0; i < 5; ++i) a[i] = fmaf(p, Xc[i], a[i]);
#pragma unroll
    for (int i = 0; i < 5; ++i) Xc[i] = Xn[i];
    vc = vn; j = jn;
  }

  float nm = xq_max(m);
  float sc = exp2_fast(m - nm);
  float D = xq_sum(d * sc);
  float A[5];
#pragma unroll
  for (int i = 0; i < 5; ++i) A[i] = xq_sum(a[i] * sc);
  if (grp == 0) {
    float inv = 1.0f / D;
    float* o = hout + (size_t)n * 20 + lg * 5;
#pragma unroll
    for (int i = 0; i < 5; ++i)
      o[i] = fmaf(A[i], inv, bias[lg * 5 + i]);
  }
}

// ==================== global add pool over sorted batch ranges ====================

__global__ __launch_bounds__(64)
void k_pool(const float* __restrict__ h, const int* __restrict__ goffs,
            float* __restrict__ out) {
  int g = blockIdx.x;
  int lane = threadIdx.x;
  if (lane >= 20) return;
  int s = goffs[g], e = goffs[g + 1];
  float sum = 0.f;
  for (int r = s; r < e; ++r) sum += h[(size_t)r * 20 + lane];
  out[g * 20 + lane] = sum;
}

// ==================== launch ====================

extern "C" void kernel_launch(void* const* d_in, const int* in_sizes, int n_in,
                              void* d_out, int out_size, void* d_ws, size_t ws_size,
                              hipStream_t stream) {
  const float* x = (const float*)d_in[0];
  const int* src = (const int*)d_in[1];
  const int* dst = src + NE;
  const int* batch = (const int*)d_in[2];
  const float *Wl[4], *bl[4], *Wr[4], *br[4], *att[4], *bb[4];
  for (int li = 0; li < 4; ++li) {
    Wl[li]  = (const float*)d_in[3 + li * 6 + 0];
    bl[li]  = (const float*)d_in[3 + li * 6 + 1];
    Wr[li]  = (const float*)d_in[3 + li * 6 + 2];
    br[li]  = (const float*)d_in[3 + li * 6 + 3];
    att[li] = (const float*)d_in[3 + li * 6 + 4];
    bb[li]  = (const float*)d_in[3 + li * 6 + 5];
  }

  char* p = (char*)d_ws;
  auto alloc = [&](size_t bytes) {
    char* r = p;
    p += (bytes + 255) & ~(size_t)255;
    return r;
  };
  unsigned short* xlbf = (unsigned short*)alloc((size_t)NN * 192 * 2);
  unsigned short* xrbf = (unsigned short*)alloc((size_t)NN * 192 * 2);
  unsigned short* hbf  = (unsigned short*)alloc((size_t)NN * 192 * 2);
  unsigned short* wb   = (unsigned short*)alloc((size_t)155136 * 2);
  int* srt   = (int*)alloc((size_t)NT * 4);
  int* offs  = (int*)alloc((size_t)(NN + 1) * 4);
  int* cnt   = (int*)alloc((size_t)NN * 4);
  int* cur   = (int*)alloc((size_t)NN * 4);
  int* bsum  = (int*)alloc((size_t)NSB * 4);
  int* goffs = (int*)alloc((size_t)(NG + 1) * 4);
  float* hpool = (float*)alloc((size_t)NN * 20 * 4);

  hipMemsetAsync(cnt, 0, (size_t)NN * 4, stream);
  hipMemsetAsync(cur, 0, (size_t)NN * 4, stream);

  k_pre<<<HB + CB + GB, 256, 0, stream>>>(dst, cnt,
                                          Wl[1], Wr[1], Wl[2], Wr[2], Wl[3], Wr[3], wb,
                                          batch, goffs);
  k_scanA<<<NSB, 1024, 0, stream>>>(cnt, offs, bsum);
  k_scanB<<<1, 1, 0, stream>>>(bsum, offs);
  k_scanC<<<NSB, 1024, 0, stream>>>(offs, bsum);
  k_scatter<<<(NT + 255) / 256, 256, 0, stream>>>(src, dst, offs, cur, srt);

  // layer 0: FI=11, FO=192 (f32 GEMM, K=11, bf16 out)
  {
    dim3 g((NN + 127) / 128, 3);
    k_gemm_dual<<<g, 256, 0, stream>>>(x, NN, 11, 192, Wl[0], bl[0], Wr[0], br[0], xlbf, xrbf);
    k_gat3<<<(NN + 3) / 4, 256, 0, stream>>>(xlbf, xrbf, att[0], bb[0], offs, srt, hbf, 1);
  }
  // layers 1,2: FI=192, FO=192 (dual bf16 MFMA GEMM, no-LDS, A-shared grid order)
  {
    dim3 gm(3, (NN + 63) / 64);
    k_gemm_mfma2<<<gm, 256, 0, stream>>>(hbf, wb + 0, wb + 36864, bl[1], br[1], xlbf, xrbf, NN, 192);
    k_gat3<<<(NN + 3) / 4, 256, 0, stream>>>(xlbf, xrbf, att[1], bb[1], offs, srt, hbf, 1);
    k_gemm_mfma2<<<gm, 256, 0, stream>>>(hbf, wb + 73728, wb + 110592, bl[2], br[2], xlbf, xrbf, NN, 192);
    k_gat3<<<(NN + 3) / 4, 256, 0, stream>>>(xlbf, xrbf, att[2], bb[2], offs, srt, hbf, 1);
  }
  // layer 3: FI=192, FO=20 (dual bf16 MFMA GEMM), dense GAT out + range pool
  {
    dim3 gm(1, (NN + 63) / 64);
    k_gemm_mfma2<<<gm, 256, 0, stream>>>(hbf, wb + 147456, wb + 151296, bl[3], br[3], xlbf, xrbf, NN, 20);
    k_gat1<<<(NN + 3) / 4, 256, 0, stream>>>(xlbf, xrbf, att[3], bb[3], offs, srt, hpool);
    k_pool<<<NG, 64, 0, stream>>>(hpool, goffs, (float*)d_out);
  }
}

// Round 14
// 517.404 us; speedup vs baseline: 1.0771x; 1.0771x over previous
//
#include <hip/hip_runtime.h>

#define NN 50000
#define NE 800000
#define NT 850000   // NE + NN self loops
#define NG 512
#define NSB 49      // scan blocks: ceil(NN/1024)

typedef __attribute__((ext_vector_type(8))) short bf16x8;
typedef __attribute__((ext_vector_type(4))) float f32x4;

// ==================== reduction / math helpers ====================

template <int CTRL>
__device__ __forceinline__ float dpp_add(float x) {
  int y = __builtin_amdgcn_update_dpp(0, __float_as_int(x), CTRL, 0xF, 0xF, true);
  return x + __int_as_float(y);
}
template <int CTRL>
__device__ __forceinline__ float dpp_max(float x) {
  int y = __builtin_amdgcn_update_dpp(0, __float_as_int(x), CTRL, 0xF, 0xF, true);
  return fmaxf(x, __int_as_float(y));
}

__device__ __forceinline__ float swz16(float x) {
  return __int_as_float(__builtin_amdgcn_ds_swizzle(__float_as_int(x), 0x401F)); // xor16
}

// sum of 16-lane row, broadcast within row (DPP only)
__device__ __forceinline__ float rowsum16(float x) {
  x = dpp_add<0xB1>(x);    // quad_perm xor1
  x = dpp_add<0x4E>(x);    // quad_perm xor2
  x = dpp_add<0x124>(x);   // row_ror:4
  x = dpp_add<0x128>(x);   // row_ror:8
  return x;
}
// sum of 4-lane quad, broadcast within quad
__device__ __forceinline__ float quadsum4(float x) {
  x = dpp_add<0xB1>(x);
  x = dpp_add<0x4E>(x);
  return x;
}
// across the 4 sixteen-lane groups (inputs row-uniform) -> wave total
__device__ __forceinline__ float xg_sum(float x) {
  x += swz16(x);
  auto p = __builtin_amdgcn_permlane32_swap(__float_as_uint(x), __float_as_uint(x), false, false);
  return __uint_as_float(p[0]) + __uint_as_float(p[1]);
}
__device__ __forceinline__ float xg_max(float x) {
  x = fmaxf(x, swz16(x));
  auto p = __builtin_amdgcn_permlane32_swap(__float_as_uint(x), __float_as_uint(x), false, false);
  return fmaxf(__uint_as_float(p[0]), __uint_as_float(p[1]));
}
// across all 16 quads (inputs quad-uniform) -> wave total
__device__ __forceinline__ float xq_sum(float x) {
  x = dpp_add<0x124>(x);
  x = dpp_add<0x128>(x);
  return xg_sum(x);
}
__device__ __forceinline__ float xq_max(float x) {
  x = dpp_max<0x124>(x);
  x = dpp_max<0x128>(x);
  return xg_max(x);
}

__device__ __forceinline__ float exp2_fast(float x) {
#if __has_builtin(__builtin_amdgcn_exp2f)
  return __builtin_amdgcn_exp2f(x);
#else
  return exp2f(x);
#endif
}

__device__ __forceinline__ float lrelu(float t) { return fmaxf(t, 0.2f * t); }

// f32 -> bf16 (RNE)
__device__ __forceinline__ unsigned int f2bf(float f) {
  unsigned int u = __float_as_uint(f);
  u = (u + 0x7FFFu + ((u >> 16) & 1u)) >> 16;
  return u;
}
// bf16 pair (u32) / quad (uint2) -> f32
__device__ __forceinline__ float bf_lo(unsigned int u) { return __uint_as_float(u << 16); }
__device__ __forceinline__ float bf_hi(unsigned int u) { return __uint_as_float(u & 0xFFFF0000u); }
__device__ __forceinline__ float4 bf2f4(uint2 u) {
  return make_float4(bf_lo(u.x), bf_hi(u.x), bf_lo(u.y), bf_hi(u.y));
}

// packed f32 FMA with broadcast halves (layer-0 GEMM)
__device__ __forceinline__ void pk_l(float2& d, float2 a, float2 b) {
  asm("v_pk_fma_f32 %0, %1, %2, %0 op_sel_hi:[0,1,1]" : "+v"(d) : "v"(a), "v"(b));
}
__device__ __forceinline__ void pk_h(float2& d, float2 a, float2 b) {
  asm("v_pk_fma_f32 %0, %1, %2, %0 op_sel:[1,0,0]" : "+v"(d) : "v"(a), "v"(b));
}

// ==================== edge bucket sort (by dst) ====================

__global__ void k_hist(const int* __restrict__ dst, int* __restrict__ cnt) {
  int i = blockIdx.x * blockDim.x + threadIdx.x;
  if (i < NT) {
    int d = (i < NE) ? dst[i] : (i - NE);
    atomicAdd(&cnt[d], 1);
  }
}

// phase A: block-local exclusive prefix into offs, block totals into bsum
__global__ __launch_bounds__(1024)
void k_scanA(const int* __restrict__ cnt, int* __restrict__ offs, int* __restrict__ bsum) {
  __shared__ int sh[1024];
  int tid = threadIdx.x;
  int idx = blockIdx.x * 1024 + tid;
  int v = (idx < NN) ? cnt[idx] : 0;
  sh[tid] = v;
  __syncthreads();
  for (int off = 1; off < 1024; off <<= 1) {
    int t = (tid >= off) ? sh[tid - off] : 0;
    __syncthreads();
    sh[tid] += t;
    __syncthreads();
  }
  if (idx < NN) offs[idx] = sh[tid] - v;   // local exclusive
  if (tid == 1023) bsum[blockIdx.x] = sh[1023];
}

// phase B: exclusive-scan the 49 block totals; write grand total to offs[NN]
__global__ void k_scanB(int* __restrict__ bsum, int* __restrict__ offs) {
  int tot = 0;
#pragma unroll 7
  for (int i = 0; i < NSB; ++i) {
    int v = bsum[i];
    bsum[i] = tot;
    tot += v;
  }
  offs[NN] = tot;
}

// phase C: add block base
__global__ __launch_bounds__(1024)
void k_scanC(int* __restrict__ offs, const int* __restrict__ bsum) {
  int idx = blockIdx.x * 1024 + threadIdx.x;
  if (idx < NN) offs[idx] += bsum[blockIdx.x];
}

// scatter via cnt-decrement (no separate cursor buffer; cnt self-zeroes)
__global__ void k_scatter(const int* __restrict__ src, const int* __restrict__ dst,
                          const int* __restrict__ offs, int* __restrict__ cnt,
                          int* __restrict__ srt) {
  int i = blockIdx.x * blockDim.x + threadIdx.x;
  if (i < NT) {
    int s, d;
    if (i < NE) { s = src[i]; d = dst[i]; }
    else        { s = d = i - NE; }
    int pos = offs[d] + atomicSub(&cnt[d], 1) - 1;
    srt[pos] = s;
  }
}

// graph offsets from sorted batch: goffs[g] = first node with batch >= g
__global__ void k_goffs(const int* __restrict__ batch, int* __restrict__ goffs) {
  int i = blockIdx.x * 256 + threadIdx.x;
  if (i >= NN) return;
  int b = batch[i];
  if (i == 0) {
    for (int g = 0; g <= b; ++g) goffs[g] = 0;
  } else {
    int pb = batch[i - 1];
    for (int g = pb + 1; g <= b; ++g) goffs[g] = i;
  }
  if (i == NN - 1) {
    for (int g = b + 1; g <= NG; ++g) goffs[g] = NN;
  }
}

// ==================== weight convert (f32 -> bf16), layers 1..3 ====================

__global__ void k_cvtW(const float* __restrict__ a, const float* __restrict__ b,
                       const float* __restrict__ c, const float* __restrict__ d,
                       const float* __restrict__ e, const float* __restrict__ f,
                       unsigned short* __restrict__ out) {
  int i = blockIdx.x * 256 + threadIdx.x;
  if (i >= 155136) return;
  float v;
  if      (i < 36864)  v = a[i];
  else if (i < 73728)  v = b[i - 36864];
  else if (i < 110592) v = c[i - 73728];
  else if (i < 147456) v = d[i - 110592];
  else if (i < 151296) v = e[i - 147456];
  else                 v = f[i - 151296];
  out[i] = (unsigned short)f2bf(v);
}

// ==================== dual MFMA GEMM (K=192, whole-K LDS resident) ====================
// C1 = A@W1^T+b1, C2 = A@W2^T+b2. Tile 64x64, 4 waves (2x2), one barrier.

#define LSTR 200  // LDS row stride in bf16 (192 + 8 pad)

__global__ __launch_bounds__(256)
void k_gemm_mfma2(const unsigned short* __restrict__ Abf,
                  const unsigned short* __restrict__ W1bf,
                  const unsigned short* __restrict__ W2bf,
                  const float* __restrict__ bias1, const float* __restrict__ bias2,
                  unsigned short* __restrict__ C1, unsigned short* __restrict__ C2,
                  int M, int FO) {
  __shared__ unsigned short Al[64 * LSTR];
  __shared__ unsigned short Bl[2][64 * LSTR];
  int tid = threadIdx.x;
  int mb = blockIdx.x * 64;
  int nb = blockIdx.y * 64;

  {
    int r = tid >> 2, q = tid & 3;
    int ga = min(mb + r, M - 1);
    int gb = min(nb + r, FO - 1);
    const unsigned short* pA = Abf  + (size_t)ga * 192 + q * 48;
    const unsigned short* p1 = W1bf + (size_t)gb * 192 + q * 48;
    const unsigned short* p2 = W2bf + (size_t)gb * 192 + q * 48;
    unsigned short* lA = Al + r * LSTR + q * 48;
    unsigned short* l1 = Bl[0] + r * LSTR + q * 48;
    unsigned short* l2 = Bl[1] + r * LSTR + q * 48;
#pragma unroll
    for (int i = 0; i < 6; ++i) {
      *(bf16x8*)(lA + i * 8) = *(const bf16x8*)(pA + i * 8);
      *(bf16x8*)(l1 + i * 8) = *(const bf16x8*)(p1 + i * 8);
      *(bf16x8*)(l2 + i * 8) = *(const bf16x8*)(p2 + i * 8);
    }
  }
  __syncthreads();

  int l = tid & 63, wid = tid >> 6;
  int wr = (wid >> 1) * 32, wc = (wid & 1) * 32;
  int lr = l & 15, lk = (l >> 4) * 8;

  f32x4 acc[2][2][2];  // [mat][fm][fn]
#pragma unroll
  for (int a = 0; a < 2; ++a)
#pragma unroll
    for (int b = 0; b < 2; ++b)
#pragma unroll
      for (int c = 0; c < 2; ++c) acc[a][b][c] = (f32x4){0.f, 0.f, 0.f, 0.f};

  const unsigned short* pa0 = Al + (wr + 0 + lr) * LSTR + lk;
  const unsigned short* pa1 = Al + (wr + 16 + lr) * LSTR + lk;
  const unsigned short* p10 = Bl[0] + (wc + 0 + lr) * LSTR + lk;
  const unsigned short* p11 = Bl[0] + (wc + 16 + lr) * LSTR + lk;
  const unsigned short* p20 = Bl[1] + (wc + 0 + lr) * LSTR + lk;
  const unsigned short* p21 = Bl[1] + (wc + 16 + lr) * LSTR + lk;
#pragma unroll
  for (int kt = 0; kt < 6; ++kt) {
    bf16x8 a0 = *(const bf16x8*)(pa0 + kt * 32);
    bf16x8 a1 = *(const bf16x8*)(pa1 + kt * 32);
    bf16x8 b10 = *(const bf16x8*)(p10 + kt * 32);
    bf16x8 b11 = *(const bf16x8*)(p11 + kt * 32);
    bf16x8 b20 = *(const bf16x8*)(p20 + kt * 32);
    bf16x8 b21 = *(const bf16x8*)(p21 + kt * 32);
    acc[0][0][0] = __builtin_amdgcn_mfma_f32_16x16x32_bf16(a0, b10, acc[0][0][0], 0, 0, 0);
    acc[0][0][1] = __builtin_amdgcn_mfma_f32_16x16x32_bf16(a0, b11, acc[0][0][1], 0, 0, 0);
    acc[0][1][0] = __builtin_amdgcn_mfma_f32_16x16x32_bf16(a1, b10, acc[0][1][0], 0, 0, 0);
    acc[0][1][1] = __builtin_amdgcn_mfma_f32_16x16x32_bf16(a1, b11, acc[0][1][1], 0, 0, 0);
    acc[1][0][0] = __builtin_amdgcn_mfma_f32_16x16x32_bf16(a0, b20, acc[1][0][0], 0, 0, 0);
    acc[1][0][1] = __builtin_amdgcn_mfma_f32_16x16x32_bf16(a0, b21, acc[1][0][1], 0, 0, 0);
    acc[1][1][0] = __builtin_amdgcn_mfma_f32_16x16x32_bf16(a1, b20, acc[1][1][0], 0, 0, 0);
    acc[1][1][1] = __builtin_amdgcn_mfma_f32_16x16x32_bf16(a1, b21, acc[1][1][1], 0, 0, 0);
  }

  // C/D layout: col = lane&15, row = (lane>>4)*4 + reg
  int rb = (l >> 4) * 4;
#pragma unroll
  for (int mt = 0; mt < 2; ++mt) {
    unsigned short* C = mt == 0 ? C1 : C2;
    const float* bias = mt == 0 ? bias1 : bias2;
#pragma unroll
    for (int fn = 0; fn < 2; ++fn) {
      int col = nb + wc + fn * 16 + lr;
      if (col >= FO) continue;
      float bv = bias[col];
#pragma unroll
      for (int fm = 0; fm < 2; ++fm) {
        const f32x4& av = acc[mt][fm][fn];
#pragma unroll
        for (int i = 0; i < 4; ++i) {
          int row = mb + wr + fm * 16 + rb + i;
          if (row < M) C[(size_t)row * FO + col] = (unsigned short)f2bf(av[i] + bv);
        }
      }
    }
  }
}

// ==================== f32 dual GEMM (layer 0, K=11) -> bf16 outputs ====================

__global__ __launch_bounds__(256)
void k_gemm_dual(const float* __restrict__ A, int M, int K, int FO,
                 const float* __restrict__ W1, const float* __restrict__ bias1,
                 const float* __restrict__ W2, const float* __restrict__ bias2,
                 unsigned short* __restrict__ C1, unsigned short* __restrict__ C2) {
  constexpr int CT = 16;
  constexpr int BN = CT * 4;
  constexpr int BR = (256 / CT) * 8;
  constexpr int AF4 = BR / 64;
  __shared__ float As[16][BR + 4];
  __shared__ float Bs[2][16][BN + 4];

  int tid = threadIdx.x;
  int tx = tid % CT, ty = tid / CT;
  int mb = blockIdx.x * BR, nb = blockIdx.y * BN;
  int nkt = (K + 15) >> 4;

  float4 sa[AF4], sb1, sb2;

  auto ldrow = [&](const float* P, int row, int lim, int k0, int kq) -> float4 {
    float4 v = make_float4(0.f, 0.f, 0.f, 0.f);
    if (row < lim) {
      float t[4];
#pragma unroll
      for (int i = 0; i < 4; ++i)
        t[i] = (k0 + kq + i < K) ? P[(size_t)row * K + k0 + kq + i] : 0.f;
      v = make_float4(t[0], t[1], t[2], t[3]);
    }
    return v;
  };

  auto loadg = [&](int kt) {
    int k0 = kt * 16;
#pragma unroll
    for (int q = 0; q < AF4; ++q) {
      int f4 = q * 256 + tid;
      sa[q] = ldrow(A, mb + (f4 >> 2), M, k0, (f4 & 3) * 4);
    }
    int row = tid >> 2, kq = (tid & 3) * 4;
    sb1 = ldrow(W1, nb + row, FO, k0, kq);
    sb2 = ldrow(W2, nb + row, FO, k0, kq);
  };

  auto stlds = [&]() {
#pragma unroll
    for (int q = 0; q < AF4; ++q) {
      int f4 = q * 256 + tid;
      int row = f4 >> 2, kq = (f4 & 3) * 4;
      As[kq + 0][row] = sa[q].x; As[kq + 1][row] = sa[q].y;
      As[kq + 2][row] = sa[q].z; As[kq + 3][row] = sa[q].w;
    }
    int row = tid >> 2, kq = (tid & 3) * 4;
    Bs[0][kq + 0][row] = sb1.x; Bs[0][kq + 1][row] = sb1.y;
    Bs[0][kq + 2][row] = sb1.z; Bs[0][kq + 3][row] = sb1.w;
    Bs[1][kq + 0][row] = sb2.x; Bs[1][kq + 1][row] = sb2.y;
    Bs[1][kq + 2][row] = sb2.z; Bs[1][kq + 3][row] = sb2.w;
  };

  float2 c1[8][2], c2[8][2];
#pragma unroll
  for (int r = 0; r < 8; ++r)
#pragma unroll
    for (int j = 0; j < 2; ++j) {
      c1[r][j] = make_float2(0.f, 0.f);
      c2[r][j] = make_float2(0.f, 0.f);
    }

  loadg(0);
  stlds();
  __syncthreads();

  for (int t = 0;;) {
#pragma unroll
    for (int k = 0; k < 16; ++k) {
      float4 av0 = *(const float4*)&As[k][ty * 8 + 0];
      float4 av1 = *(const float4*)&As[k][ty * 8 + 4];
      float4 bv1 = *(const float4*)&Bs[0][k][tx * 4];
      float4 bv2 = *(const float4*)&Bs[1][k][tx * 4];
      float2 f1a = make_float2(bv1.x, bv1.y), f1b = make_float2(bv1.z, bv1.w);
      float2 f2a = make_float2(bv2.x, bv2.y), f2b = make_float2(bv2.z, bv2.w);
      float2 a01 = make_float2(av0.x, av0.y), a23 = make_float2(av0.z, av0.w);
      float2 a45 = make_float2(av1.x, av1.y), a67 = make_float2(av1.z, av1.w);
#define PKROW(rp, a)                                                       \
      pk_l(c1[2 * rp + 0][0], a, f1a); pk_l(c1[2 * rp + 0][1], a, f1b);    \
      pk_h(c1[2 * rp + 1][0], a, f1a); pk_h(c1[2 * rp + 1][1], a, f1b);    \
      pk_l(c2[2 * rp + 0][0], a, f2a); pk_l(c2[2 * rp + 0][1], a, f2b);    \
      pk_h(c2[2 * rp + 1][0], a, f2a); pk_h(c2[2 * rp + 1][1], a, f2b);
      PKROW(0, a01) PKROW(1, a23) PKROW(2, a45) PKROW(3, a67)
#undef PKROW
    }
    if (++t == nkt) break;
    loadg(t);
    __syncthreads();
    stlds();
    __syncthreads();
  }

  int col = nb + tx * 4;
  if (col < FO) {
    float4 bb1 = *(const float4*)&bias1[col];
    float4 bb2 = *(const float4*)&bias2[col];
#pragma unroll
    for (int r = 0; r < 8; ++r) {
      int m = mb + ty * 8 + r;
      if (m >= M) continue;
      uint2 o1, o2;
      o1.x = f2bf(c1[r][0].x + bb1.x) | (f2bf(c1[r][0].y + bb1.y) << 16);
      o1.y = f2bf(c1[r][1].x + bb1.z) | (f2bf(c1[r][1].y + bb1.w) << 16);
      o2.x = f2bf(c2[r][0].x + bb2.x) | (f2bf(c2[r][0].y + bb2.y) << 16);
      o2.y = f2bf(c2[r][1].x + bb2.z) | (f2bf(c2[r][1].y + bb2.w) << 16);
      *(uint2*)&C1[(size_t)m * FO + col] = o1;
      *(uint2*)&C2[(size_t)m * FO + col] = o2;
    }
  }
}

// ==================== GAT H=3 C=64: 4 edges/wave, bf16 gather (R10 proven version) ====================
// 256-thread block = 4 waves = 4 nodes. group g = lanes [16g,16g+16) owns
// edge e0+4*it+g; lane owns 4 ch/head.

__global__ __launch_bounds__(256)
void k_gat3(const unsigned short* __restrict__ xl, const unsigned short* __restrict__ xr,
            const float* __restrict__ att, const float* __restrict__ bias,
            const int* __restrict__ offs, const int* __restrict__ srt,
            unsigned short* __restrict__ obf, int relu) {
  const float L2E = 1.4426950408889634f;
  int lane = threadIdx.x & 63;
  int grp = lane >> 4, lg = lane & 15;
  int n = blockIdx.x * 4 + (threadIdx.x >> 6);
  if (n >= NN) return;

  float4 xrv[3], atv[3];
#pragma unroll
  for (int h = 0; h < 3; ++h) {
    xrv[h] = bf2f4(*(const uint2*)(xr + (size_t)n * 192 + h * 64 + lg * 4));
    float4 a = *(const float4*)&att[h * 64 + lg * 4];
    atv[h] = make_float4(a.x * L2E, a.y * L2E, a.z * L2E, a.w * L2E);
  }
  float m[3] = {-1e30f, -1e30f, -1e30f}, d[3] = {0.f, 0.f, 0.f};
  float4 acc[3];
#pragma unroll
  for (int h = 0; h < 3; ++h) acc[h] = make_float4(0.f, 0.f, 0.f, 0.f);

  int e0 = offs[n], e1 = offs[n + 1];
  int nch = (e1 - e0 + 3) >> 2;

  uint2 Rc[3];
  bool vc;
  int j = e0 + grp;
  {
    int jj = min(j, e1 - 1);
    int s = srt[jj];
    const unsigned short* b = xl + (size_t)s * 192 + lg * 4;
    Rc[0] = *(const uint2*)(b);
    Rc[1] = *(const uint2*)(b + 64);
    Rc[2] = *(const uint2*)(b + 128);
    vc = j < e1;
  }
  for (int it = 0; it < nch; ++it) {
    uint2 Rn[3];
    bool vn = false;
    int jn = j + 4;
    if (it + 1 < nch) {
      int jj = min(jn, e1 - 1);
      int s = srt[jj];
      const unsigned short* b = xl + (size_t)s * 192 + lg * 4;
      Rn[0] = *(const uint2*)(b);
      Rn[1] = *(const uint2*)(b + 64);
      Rn[2] = *(const uint2*)(b + 128);
      vn = jn < e1;
    }
    float4 Xc[3];
    Xc[0] = bf2f4(Rc[0]); Xc[1] = bf2f4(Rc[1]); Xc[2] = bf2f4(Rc[2]);
    float part[3];
#pragma unroll
    for (int h = 0; h < 3; ++h) {
      float t = lrelu(Xc[h].x + xrv[h].x);
      float pa = t * atv[h].x;
      t = lrelu(Xc[h].y + xrv[h].y); pa = fmaf(t, atv[h].y, pa);
      t = lrelu(Xc[h].z + xrv[h].z); pa = fmaf(t, atv[h].z, pa);
      t = lrelu(Xc[h].w + xrv[h].w); pa = fmaf(t, atv[h].w, pa);
      part[h] = pa;
    }
#pragma unroll
    for (int h = 0; h < 3; ++h) {
      part[h] = rowsum16(part[h]);
      part[h] = vc ? part[h] : -1e30f;
    }
    float g = fmaxf(fmaxf(part[0] - m[0], part[1] - m[1]), part[2] - m[2]);
    if (__any(g > 11.0f)) {   // rare rescale (defer-max), log2 domain
#pragma unroll
      for (int h = 0; h < 3; ++h) {
        float nm = fmaxf(m[h], part[h]);
        float sc = exp2_fast(m[h] - nm);
        d[h] *= sc;
        acc[h].x *= sc; acc[h].y *= sc; acc[h].z *= sc; acc[h].w *= sc;
        m[h] = nm;
      }
    }
#pragma unroll
    for (int h = 0; h < 3; ++h) {
      float p = vc ? exp2_fast(part[h] - m[h]) : 0.f;
      d[h] += p;
      acc[h].x = fmaf(p, Xc[h].x, acc[h].x);
      acc[h].y = fmaf(p, Xc[h].y, acc[h].y);
      acc[h].z = fmaf(p, Xc[h].z, acc[h].z);
      acc[h].w = fmaf(p, Xc[h].w, acc[h].w);
    }
    Rc[0] = Rn[0]; Rc[1] = Rn[1]; Rc[2] = Rn[2];
    vc = vn; j = jn;
  }

  // combine the 4 group-partials (once per node)
#pragma unroll
  for (int h = 0; h < 3; ++h) {
    float nm = xg_max(m[h]);
    float sc = exp2_fast(m[h] - nm);
    float D = xg_sum(d[h] * sc);
    float A0 = xg_sum(acc[h].x * sc);
    float A1 = xg_sum(acc[h].y * sc);
    float A2 = xg_sum(acc[h].z * sc);
    float A3 = xg_sum(acc[h].w * sc);
    if (grp == 0) {
      float4 bb = *(const float4*)&bias[h * 64 + lg * 4];
      float inv = 1.0f / D;
      float v0 = fmaf(A0, inv, bb.x);
      float v1 = fmaf(A1, inv, bb.y);
      float v2 = fmaf(A2, inv, bb.z);
      float v3 = fmaf(A3, inv, bb.w);
      if (relu) {
        v0 = fmaxf(v0, 0.f); v1 = fmaxf(v1, 0.f);
        v2 = fmaxf(v2, 0.f); v3 = fmaxf(v3, 0.f);
      }
      unsigned int lo = f2bf(v0) | (f2bf(v1) << 16);
      unsigned int hi = f2bf(v2) | (f2bf(v3) << 16);
      *(uint2*)(obf + (size_t)n * 192 + h * 64 + lg * 4) = make_uint2(lo, hi);
    }
  }
}

// ==================== GAT layer 3 (H=1, C=20): dense per-node output ====================

__global__ __launch_bounds__(256)
void k_gat1(const unsigned short* __restrict__ xl, const unsigned short* __restrict__ xr,
            const float* __restrict__ att, const float* __restrict__ bias,
            const int* __restrict__ offs, const int* __restrict__ srt,
            float* __restrict__ hout) {
  const float L2E = 1.4426950408889634f;
  int lane = threadIdx.x & 63;
  int grp = lane >> 2, lg = lane & 3;
  int n = blockIdx.x * 4 + (threadIdx.x >> 6);
  if (n >= NN) return;

  float xrv[5], atv[5];
#pragma unroll
  for (int i = 0; i < 5; ++i) {
    xrv[i] = bf_lo(xr[(size_t)n * 20 + lg * 5 + i]);
    atv[i] = att[lg * 5 + i] * L2E;
  }
  float m = -1e30f, d = 0.f, a[5] = {0.f, 0.f, 0.f, 0.f, 0.f};

  int e0 = offs[n], e1 = offs[n + 1];
  int nch = (e1 - e0 + 15) >> 4;

  float Xc[5];
  bool vc;
  int j = e0 + grp;
  {
    int jj = min(j, e1 - 1);
    int s = srt[jj];
    const unsigned short* b = xl + (size_t)s * 20 + lg * 5;
#pragma unroll
    for (int i = 0; i < 5; ++i) Xc[i] = bf_lo(b[i]);
    vc = j < e1;
  }
  for (int it = 0; it < nch; ++it) {
    float Xn[5] = {0.f, 0.f, 0.f, 0.f, 0.f};
    bool vn = false;
    int jn = j + 16;
    if (it + 1 < nch) {
      int jj = min(jn, e1 - 1);
      int s = srt[jj];
      const unsigned short* b = xl + (size_t)s * 20 + lg * 5;
#pragma unroll
      for (int i = 0; i < 5; ++i) Xn[i] = bf_lo(b[i]);
      vn = jn < e1;
    }
    float pa = lrelu(Xc[0] + xrv[0]) * atv[0];
#pragma unroll
    for (int i = 1; i < 5; ++i) pa = fmaf(lrelu(Xc[i] + xrv[i]), atv[i], pa);
    pa = quadsum4(pa);
    pa = vc ? pa : -1e30f;
    if (__any(pa - m > 11.0f)) {
      float nm = fmaxf(m, pa);
      float sc = exp2_fast(m - nm);
      d *= sc;
#pragma unroll
      for (int i = 0; i < 5; ++i) a[i] *= sc;
      m = nm;
    }
    float p = vc ? exp2_fast(pa - m) : 0.f;
    d += p;
#pragma unroll
    for (int i = 0; i < 5; ++i) a[i] = fmaf(p, Xc[i], a[i]);
#pragma unroll
    for (int i = 0; i < 5; ++i) Xc[i] = Xn[i];
    vc = vn; j = jn;
  }

  float nm = xq_max(m);
  float sc = exp2_fast(m - nm);
  float D = xq_sum(d * sc);
  float A[5];
#pragma unroll
  for (int i = 0; i < 5; ++i) A[i] = xq_sum(a[i] * sc);
  if (grp == 0) {
    float inv = 1.0f / D;
    float* o = hout + (size_t)n * 20 + lg * 5;
#pragma unroll
    for (int i = 0; i < 5; ++i)
      o[i] = fmaf(A[i], inv, bias[lg * 5 + i]);
  }
}

// ==================== global add pool over sorted batch ranges ====================

__global__ __launch_bounds__(64)
void k_pool(const float* __restrict__ h, const int* __restrict__ goffs,
            float* __restrict__ out) {
  int g = blockIdx.x;
  int lane = threadIdx.x;
  if (lane >= 20) return;
  int s = goffs[g], e = goffs[g + 1];
  float sum = 0.f;
  for (int r = s; r < e; ++r) sum += h[(size_t)r * 20 + lane];
  out[g * 20 + lane] = sum;
}

// ==================== launch ====================

extern "C" void kernel_launch(void* const* d_in, const int* in_sizes, int n_in,
                              void* d_out, int out_size, void* d_ws, size_t ws_size,
                              hipStream_t stream) {
  const float* x = (const float*)d_in[0];
  const int* src = (const int*)d_in[1];
  const int* dst = src + NE;
  const int* batch = (const int*)d_in[2];
  const float *Wl[4], *bl[4], *Wr[4], *br[4], *att[4], *bb[4];
  for (int li = 0; li < 4; ++li) {
    Wl[li]  = (const float*)d_in[3 + li * 6 + 0];
    bl[li]  = (const float*)d_in[3 + li * 6 + 1];
    Wr[li]  = (const float*)d_in[3 + li * 6 + 2];
    br[li]  = (const float*)d_in[3 + li * 6 + 3];
    att[li] = (const float*)d_in[3 + li * 6 + 4];
    bb[li]  = (const float*)d_in[3 + li * 6 + 5];
  }

  char* p = (char*)d_ws;
  auto alloc = [&](size_t bytes) {
    char* r = p;
    p += (bytes + 255) & ~(size_t)255;
    return r;
  };
  unsigned short* xlbf = (unsigned short*)alloc((size_t)NN * 192 * 2);
  unsigned short* xrbf = (unsigned short*)alloc((size_t)NN * 192 * 2);
  unsigned short* hbf  = (unsigned short*)alloc((size_t)NN * 192 * 2);
  unsigned short* wb   = (unsigned short*)alloc((size_t)155136 * 2);
  int* srt   = (int*)alloc((size_t)NT * 4);
  int* offs  = (int*)alloc((size_t)(NN + 1) * 4);
  int* cnt   = (int*)alloc((size_t)NN * 4);
  int* bsum  = (int*)alloc((size_t)NSB * 4);
  int* goffs = (int*)alloc((size_t)(NG + 1) * 4);
  float* hpool = (float*)alloc((size_t)NN * 20 * 4);

  hipMemsetAsync(cnt, 0, (size_t)NN * 4, stream);

  k_hist<<<(NT + 255) / 256, 256, 0, stream>>>(dst, cnt);
  k_scanA<<<NSB, 1024, 0, stream>>>(cnt, offs, bsum);
  k_scanB<<<1, 1, 0, stream>>>(bsum, offs);
  k_scanC<<<NSB, 1024, 0, stream>>>(offs, bsum);
  k_scatter<<<(NT + 255) / 256, 256, 0, stream>>>(src, dst, offs, cnt, srt);
  k_goffs<<<(NN + 255) / 256, 256, 0, stream>>>(batch, goffs);
  k_cvtW<<<(155136 + 255) / 256, 256, 0, stream>>>(Wl[1], Wr[1], Wl[2], Wr[2], Wl[3], Wr[3], wb);

  // layer 0: FI=11, FO=192 (f32 GEMM, K=11, bf16 out)
  {
    dim3 g((NN + 127) / 128, 3);
    k_gemm_dual<<<g, 256, 0, stream>>>(x, NN, 11, 192, Wl[0], bl[0], Wr[0], br[0], xlbf, xrbf);
    k_gat3<<<(NN + 3) / 4, 256, 0, stream>>>(xlbf, xrbf, att[0], bb[0], offs, srt, hbf, 1);
  }
  // layers 1,2: FI=192, FO=192 (dual bf16 MFMA GEMM)
  {
    dim3 gm((NN + 63) / 64, 3);
    k_gemm_mfma2<<<gm, 256, 0, stream>>>(hbf, wb + 0, wb + 36864, bl[1], br[1], xlbf, xrbf, NN, 192);
    k_gat3<<<(NN + 3) / 4, 256, 0, stream>>>(xlbf, xrbf, att[1], bb[1], offs, srt, hbf, 1);
    k_gemm_mfma2<<<gm, 256, 0, stream>>>(hbf, wb + 73728, wb + 110592, bl[2], br[2], xlbf, xrbf, NN, 192);
    k_gat3<<<(NN + 3) / 4, 256, 0, stream>>>(xlbf, xrbf, att[2], bb[2], offs, srt, hbf, 1);
  }
  // layer 3: FI=192, FO=20 (dual bf16 MFMA GEMM), dense GAT out + range pool
  {
    dim3 gm((NN + 63) / 64, 1);
    k_gemm_mfma2<<<gm, 256, 0, stream>>>(hbf, wb + 147456, wb + 151296, bl[3], br[3], xlbf, xrbf, NN, 20);
    k_gat1<<<(NN + 3) / 4, 256, 0, stream>>>(xlbf, xrbf, att[3], bb[3], offs, srt, hpool);
    k_pool<<<NG, 64, 0, stream>>>(hpool, goffs, (float*)d_out);
  }
}